// Round 5
// baseline (239.126 us; speedup 1.0000x reference)
//
#include <hip/hip_runtime.h>

// SwitchTransformersLoadBalancer:
//   x: (B=64, C=8, H=256, W=256) f32, accumulator: (256, 8) f32
//   out = one_hot(argmax_c (x_c - log(mean(acc[:,c]))))   [proved R0/R1, absmax 0]
// R7: attack HBM stream fragmentation. R6 post-mortem: VALUBusy 8->34% at zero
//   time cost (VALU fully hidden), barriers/LDS removal = null, occupancy not
//   reg-capped -- kernel pinned at 2.5 TB/s by the memory system itself.
//   Theory: each R6 wave touched 16 isolated 1 KB chunks at 256 KB stride ->
//   controller-visible stream is maximally fragmented (row ACT/PRE per chunk).
//   R7 keeps the barrier-free structure but doubles the per-plane run length:
//   2 adjacent fvec4-groups per thread, ALL 24 loads (8 acc + 16 x) issued
//   before any consumption; butterfly+logs consume acc at vmcnt(16) while x
//   streams; then argmax+store per group. Block covers 8 KB contiguous/plane.

#define PLANE4 16384   // plane stride in float4 units (65536 floats)

typedef float fvec4 __attribute__((ext_vector_type(4)));

__global__ __launch_bounds__(256) void fused_route_kernel(
        const float* __restrict__ x,
        const float* __restrict__ acc,
        float* __restrict__ out) {
    int t     = threadIdx.x;
    int lane  = t & 63;
    int base4 = blockIdx.x << 9;      // 512 fvec4 per block (256 thr x 2 groups)
    int b     = base4 >> 14;          // 16384 fvec4 per plane -> block-uniform batch
    int p4    = (base4 & 16383) + t;  // group-0 fvec4 offset inside plane

    const fvec4* accv = (const fvec4*)acc;          // 512 fvec4 total (8 KB)
    const fvec4* xb   = (const fvec4*)(x + ((size_t)(b * 8) << 16));
    fvec4*       ob   = (fvec4*)(out + ((size_t)(b * 8) << 16));

    // ---- acc loads FIRST (oldest in vmcnt queue; L2/LLC-resident) ----
    fvec4 a0 = accv[4 * lane + 0];
    fvec4 a1 = accv[4 * lane + 1];
    fvec4 a2 = accv[4 * lane + 2];
    fvec4 a3 = accv[4 * lane + 3];
    fvec4 b0 = accv[256 + 4 * lane + 0];
    fvec4 b1 = accv[256 + 4 * lane + 1];
    fvec4 b2 = accv[256 + 4 * lane + 2];
    fvec4 b3 = accv[256 + 4 * lane + 3];

    // ---- all 16 x loads issued back-to-back: two adjacent 1 KB wave-chunks
    //      per plane -> longer sequential runs for the memory controllers ----
    fvec4 u[8], v[8];
    #pragma unroll
    for (int c = 0; c < 8; ++c) u[c] = xb[p4 + c * PLANE4];
    #pragma unroll
    for (int c = 0; c < 8; ++c) v[c] = xb[p4 + 256 + c * PLANE4];

    // ---- per-lane partial sums (4 rows, all 8 channels), f64 ----
    double s[8];
    s[0] = (double)a0.x + (double)a2.x + (double)b0.x + (double)b2.x;
    s[1] = (double)a0.y + (double)a2.y + (double)b0.y + (double)b2.y;
    s[2] = (double)a0.z + (double)a2.z + (double)b0.z + (double)b2.z;
    s[3] = (double)a0.w + (double)a2.w + (double)b0.w + (double)b2.w;
    s[4] = (double)a1.x + (double)a3.x + (double)b1.x + (double)b3.x;
    s[5] = (double)a1.y + (double)a3.y + (double)b1.y + (double)b3.y;
    s[6] = (double)a1.z + (double)a3.z + (double)b1.z + (double)b3.z;
    s[7] = (double)a1.w + (double)a3.w + (double)b1.w + (double)b3.w;

    // ---- wave butterfly: full 256-row sum per channel, identical on all lanes ----
    #pragma unroll
    for (int m = 1; m < 64; m <<= 1) {
        #pragma unroll
        for (int c = 0; c < 8; ++c) s[c] += __shfl_xor(s[c], m, 64);
    }

    // ---- lognorm (hidden under x-load latency; proven R6) ----
    double ln[8];
    #pragma unroll
    for (int c = 0; c < 8; ++c) ln[c] = log(s[c] * (1.0 / 256.0));

    // ---- group 0: f64 argmax + nt one-hot stores ----
    {
        double best0 = (double)u[0].x - ln[0];
        double best1 = (double)u[0].y - ln[0];
        double best2 = (double)u[0].z - ln[0];
        double best3 = (double)u[0].w - ln[0];
        int idx0 = 0, idx1 = 0, idx2 = 0, idx3 = 0;
        #pragma unroll
        for (int c = 1; c < 8; ++c) {
            double d;
            d = (double)u[c].x - ln[c]; if (d > best0) { best0 = d; idx0 = c; }
            d = (double)u[c].y - ln[c]; if (d > best1) { best1 = d; idx1 = c; }
            d = (double)u[c].z - ln[c]; if (d > best2) { best2 = d; idx2 = c; }
            d = (double)u[c].w - ln[c]; if (d > best3) { best3 = d; idx3 = c; }
        }
        #pragma unroll
        for (int c = 0; c < 8; ++c) {
            fvec4 o;
            o.x = (idx0 == c) ? 1.0f : 0.0f;
            o.y = (idx1 == c) ? 1.0f : 0.0f;
            o.z = (idx2 == c) ? 1.0f : 0.0f;
            o.w = (idx3 == c) ? 1.0f : 0.0f;
            __builtin_nontemporal_store(o, ob + p4 + c * PLANE4);
        }
    }

    // ---- group 1: same, at p4+256 ----
    {
        double best0 = (double)v[0].x - ln[0];
        double best1 = (double)v[0].y - ln[0];
        double best2 = (double)v[0].z - ln[0];
        double best3 = (double)v[0].w - ln[0];
        int idx0 = 0, idx1 = 0, idx2 = 0, idx3 = 0;
        #pragma unroll
        for (int c = 1; c < 8; ++c) {
            double d;
            d = (double)v[c].x - ln[c]; if (d > best0) { best0 = d; idx0 = c; }
            d = (double)v[c].y - ln[c]; if (d > best1) { best1 = d; idx1 = c; }
            d = (double)v[c].z - ln[c]; if (d > best2) { best2 = d; idx2 = c; }
            d = (double)v[c].w - ln[c]; if (d > best3) { best3 = d; idx3 = c; }
        }
        #pragma unroll
        for (int c = 0; c < 8; ++c) {
            fvec4 o;
            o.x = (idx0 == c) ? 1.0f : 0.0f;
            o.y = (idx1 == c) ? 1.0f : 0.0f;
            o.z = (idx2 == c) ? 1.0f : 0.0f;
            o.w = (idx3 == c) ? 1.0f : 0.0f;
            __builtin_nontemporal_store(o, ob + p4 + 256 + c * PLANE4);
        }
    }
}

extern "C" void kernel_launch(void* const* d_in, const int* in_sizes, int n_in,
                              void* d_out, int out_size, void* d_ws, size_t ws_size,
                              hipStream_t stream) {
    const float* x   = (const float*)d_in[0];   // (64, 8, 256, 256)
    const float* acc = (const float*)d_in[1];   // (256, 8)
    float*       out = (float*)d_out;           // (64, 8, 256, 256)
    (void)d_ws; (void)ws_size;

    // B*H*W/4 = 1,048,576 fvec4; 2 fvec4/thread -> 2048 blocks x 256 threads.
    fused_route_kernel<<<2048, 256, 0, stream>>>(x, acc, out);
}

// Round 6
// 226.548 us; speedup vs baseline: 1.0555x; 1.0555x over previous
//
#include <hip/hip_runtime.h>

// SwitchTransformersLoadBalancer:
//   x: (B=64, C=8, H=256, W=256) f32, accumulator: (256, 8) f32
//   out = one_hot(argmax_c (x_c - log(mean(acc[:,c]))))   [proved R0/R1, absmax 0]
// R8: reconstruct the session-best R3 config (1024 blocks x 4 groups, NT loads,
//   depth-2 pipeline; inferred kernel ~67 us) with two proven-free upgrades:
//   barrier-free wave reduce (R6) and group-1 loads issued before the reduce.
//   KEY FIX vs R5-R7: __launch_bounds__(256,2) caps VGPR at 128 so the
//   compiler can hold BOTH pipeline buffers (R6/R7 came back at 36/44 VGPRs --
//   it was sinking loads to save registers, serializing every pipeline).
//   Pipeline: acc(8) -> loadA(g0) -> loadB(g1) -> reduce [vmcnt leaves 16 x
//   in flight] -> procA(g0) -> loadA(g2) -> procB(g1) -> loadB(g3) -> procA ->
//   procB.  No LDS, no barriers anywhere.

#define PLANE4 16384   // plane stride in float4 units (65536 floats)

typedef float fvec4 __attribute__((ext_vector_type(4)));

__device__ __forceinline__ void load_group_nt(fvec4 (&u)[8], const fvec4* __restrict__ xb,
                                              int p4) {
    #pragma unroll
    for (int c = 0; c < 8; ++c)
        u[c] = __builtin_nontemporal_load(xb + p4 + c * PLANE4);
}

__device__ __forceinline__ void proc_group(const fvec4 (&u)[8], const double (&ln)[8],
                                           fvec4* __restrict__ ob, int p4) {
    // f64 argmax (exact vs f32 reference; strict > = first-index ties)
    double best0 = (double)u[0].x - ln[0];
    double best1 = (double)u[0].y - ln[0];
    double best2 = (double)u[0].z - ln[0];
    double best3 = (double)u[0].w - ln[0];
    int idx0 = 0, idx1 = 0, idx2 = 0, idx3 = 0;

    #pragma unroll
    for (int c = 1; c < 8; ++c) {
        double d;
        d = (double)u[c].x - ln[c]; if (d > best0) { best0 = d; idx0 = c; }
        d = (double)u[c].y - ln[c]; if (d > best1) { best1 = d; idx1 = c; }
        d = (double)u[c].z - ln[c]; if (d > best2) { best2 = d; idx2 = c; }
        d = (double)u[c].w - ln[c]; if (d > best3) { best3 = d; idx3 = c; }
    }

    #pragma unroll
    for (int c = 0; c < 8; ++c) {
        fvec4 o;
        o.x = (idx0 == c) ? 1.0f : 0.0f;
        o.y = (idx1 == c) ? 1.0f : 0.0f;
        o.z = (idx2 == c) ? 1.0f : 0.0f;
        o.w = (idx3 == c) ? 1.0f : 0.0f;
        __builtin_nontemporal_store(o, ob + p4 + c * PLANE4);
    }
}

__global__ __launch_bounds__(256, 2) void fused_route_kernel(
        const float* __restrict__ x,
        const float* __restrict__ acc,
        float* __restrict__ out) {
    int t     = threadIdx.x;
    int lane  = t & 63;
    int base4 = blockIdx.x << 10;     // 1024 fvec4 per block (256 thr x 4 groups)
    int b     = base4 >> 14;          // 16384 fvec4 per plane -> block-uniform batch
    int p4    = (base4 & 16383) + t;  // group-0 fvec4 offset inside plane

    const fvec4* accv = (const fvec4*)acc;          // 512 fvec4 total (8 KB)
    const fvec4* xb   = (const fvec4*)(x + ((size_t)(b * 8) << 16));
    fvec4*       ob   = (fvec4*)(out + ((size_t)(b * 8) << 16));

    // ---- acc loads FIRST (oldest in vmcnt queue; L2-resident, plain) ----
    fvec4 a0 = accv[4 * lane + 0];
    fvec4 a1 = accv[4 * lane + 1];
    fvec4 a2 = accv[4 * lane + 2];
    fvec4 a3 = accv[4 * lane + 3];
    fvec4 b0 = accv[256 + 4 * lane + 0];
    fvec4 b1 = accv[256 + 4 * lane + 1];
    fvec4 b2 = accv[256 + 4 * lane + 2];
    fvec4 b3 = accv[256 + 4 * lane + 3];

    // ---- groups 0 and 1 issued before the reduce: 16 x-loads in flight ----
    fvec4 ua[8], ub[8];
    load_group_nt(ua, xb, p4);
    load_group_nt(ub, xb, p4 + 256);

    // ---- per-lane partial sums (4 rows, all 8 channels), f64 ----
    double s[8];
    s[0] = (double)a0.x + (double)a2.x + (double)b0.x + (double)b2.x;
    s[1] = (double)a0.y + (double)a2.y + (double)b0.y + (double)b2.y;
    s[2] = (double)a0.z + (double)a2.z + (double)b0.z + (double)b2.z;
    s[3] = (double)a0.w + (double)a2.w + (double)b0.w + (double)b2.w;
    s[4] = (double)a1.x + (double)a3.x + (double)b1.x + (double)b3.x;
    s[5] = (double)a1.y + (double)a3.y + (double)b1.y + (double)b3.y;
    s[6] = (double)a1.z + (double)a3.z + (double)b1.z + (double)b3.z;
    s[7] = (double)a1.w + (double)a3.w + (double)b1.w + (double)b3.w;

    // ---- wave butterfly: full 256-row sum per channel, identical on all lanes ----
    #pragma unroll
    for (int m = 1; m < 64; m <<= 1) {
        #pragma unroll
        for (int c = 0; c < 8; ++c) s[c] += __shfl_xor(s[c], m, 64);
    }

    // ---- lognorm (hidden under the 16 in-flight x loads) ----
    double ln[8];
    #pragma unroll
    for (int c = 0; c < 8; ++c) ln[c] = log(s[c] * (1.0 / 256.0));

    // ---- depth-2 pipeline over 4 groups ----
    proc_group(ua, ln, ob, p4);             // consumes g0 (vmcnt leaves g1)
    load_group_nt(ua, xb, p4 + 512);        // g2 in flight
    proc_group(ub, ln, ob, p4 + 256);       // consumes g1 (vmcnt leaves g2)
    load_group_nt(ub, xb, p4 + 768);        // g3 in flight
    proc_group(ua, ln, ob, p4 + 512);       // consumes g2 (vmcnt leaves g3)
    proc_group(ub, ln, ob, p4 + 768);       // consumes g3
}

extern "C" void kernel_launch(void* const* d_in, const int* in_sizes, int n_in,
                              void* d_out, int out_size, void* d_ws, size_t ws_size,
                              hipStream_t stream) {
    const float* x   = (const float*)d_in[0];   // (64, 8, 256, 256)
    const float* acc = (const float*)d_in[1];   // (256, 8)
    float*       out = (float*)d_out;           // (64, 8, 256, 256)
    (void)d_ws; (void)ws_size;

    // B*H*W/4 = 1,048,576 fvec4; 4 fvec4/thread -> 1024 blocks x 256 threads.
    fused_route_kernel<<<1024, 256, 0, stream>>>(x, acc, out);
}